// Round 7
// baseline (275.269 us; speedup 1.0000x reference)
//
#include <hip/hip_runtime.h>
#include <hip/hip_bf16.h>

typedef unsigned short u16;
typedef __attribute__((ext_vector_type(8))) short short8;
typedef __attribute__((ext_vector_type(4))) float f32x4;
typedef __attribute__((ext_vector_type(16))) float f32x16;
typedef __attribute__((ext_vector_type(4))) int i32x4;
typedef __attribute__((ext_vector_type(2))) int i32x2;

#define MFMA16(a,b,c) __builtin_amdgcn_mfma_f32_16x16x32_bf16((a),(b),(c),0,0,0)
#define MFMA32(a,b,c) __builtin_amdgcn_mfma_f32_32x32x16_bf16((a),(b),(c),0,0,0)

__device__ __forceinline__ u16 f2bf(float f) {
  union { float f; unsigned int u; } x; x.f = f;
  unsigned int u = x.u;
  return (u16)((u + 0x7fffu + ((u >> 16) & 1u)) >> 16);  // RNE
}

// v_cvt_pk_bf16_f32: dst = {hi: bf16(b), lo: bf16(a)}
__device__ __forceinline__ unsigned cvtpk(float a, float b) {
  unsigned r;
  asm("v_cvt_pk_bf16_f32 %0, %1, %2" : "=v"(r) : "v"(a), "v"(b));
  return r;
}

// v_exp_f32: 2^x
__device__ __forceinline__ float exp2v(float x) {
  float r;
  asm("v_exp_f32 %0, %1" : "=v"(r) : "v"(x));
  return r;
}

// async global->LDS, 16B per lane (dst = wave-uniform base + lane*16)
__device__ __forceinline__ void gld16(const void* g, void* l) {
  __builtin_amdgcn_global_load_lds(
      (const __attribute__((address_space(1))) void*)g,
      (__attribute__((address_space(3))) void*)l, 16, 0, 0);
}

// ---------------- fused preprocessing ----------------------------------------
__global__ __launch_bounds__(256) void prep(
    const float* __restrict__ x, u16* __restrict__ xb,
    const float* __restrict__ u, u16* __restrict__ ub,
    const float* __restrict__ Wqkv, u16* __restrict__ Wqkvt,
    const float* __restrict__ Wout, u16* __restrict__ Woutt,
    const float* __restrict__ vlr, u16* __restrict__ vTb) {
  __shared__ float tile[32][33];
  int bid = blockIdx.x, tid = threadIdx.x;
  if (bid < 4112) {
    const float* in; u16* out; size_t i; float sc;
    if (bid < 4096) { in = x; out = xb; i = (size_t)bid * 256 + tid; sc = 1.f; }
    else { in = u; out = ub; i = (size_t)(bid - 4096) * 256 + tid; sc = 1.44269504f; }
    f32x4 a = *(const f32x4*)(in + i * 8);
    f32x4 b = *(const f32x4*)(in + i * 8 + 4);
    union { short8 s; u16 us[8]; } r;
    #pragma unroll
    for (int j = 0; j < 4; ++j) { r.us[j] = f2bf(a[j] * sc); r.us[4 + j] = f2bf(b[j] * sc); }
    *(short8*)&out[i * 8] = r.s;
    return;
  }
  int tb = bid - 4112;
  const float* in; u16* out; int rows, cols, bx, by;
  if (tb < 768)       { in = Wqkv; out = Wqkvt; rows = 512; cols = 1536; bx = tb % 48; by = tb / 48; }
  else if (tb < 1024) { int q = tb - 768; in = Wout; out = Woutt; rows = 512; cols = 512; bx = q % 16; by = q / 16; }
  else                { in = vlr; out = vTb; rows = 32; cols = 1024; bx = tb - 1024; by = 0; }
  int bc = bx * 32, br = by * 32;
  int tx = tid & 31, ty = tid >> 5;
  #pragma unroll
  for (int i = ty; i < 32; i += 8)
    tile[i][tx] = in[(size_t)(br + i) * cols + bc + tx];
  __syncthreads();
  #pragma unroll
  for (int i = ty; i < 32; i += 8)
    out[(size_t)(bc + i) * rows + br + tx] = f2bf(tile[tx][i]);
}

// ---------------- GEMM 128x128 tile, BK=64, 4 waves, global_load_lds ---------
// (unchanged from round 6 — m99/m100 predict dbuf is neutral at this occupancy)
template<int MODE>
__global__ __launch_bounds__(256) void gemm128(
    const u16* __restrict__ A, const u16* __restrict__ Bt,
    const float* __restrict__ bias,
    u16* __restrict__ oq, u16* __restrict__ ok, u16* __restrict__ ov,
    float* __restrict__ fo) {
  const int K = 512;
  __shared__ __align__(16) u16 As[128 * 64];
  __shared__ __align__(16) u16 Bs[128 * 64];
  int tid = threadIdx.x;
  int w = tid >> 6, ln = tid & 63, lo = ln & 15, hi = ln >> 4;
  int wr = (w >> 1) * 64, wc = (w & 1) * 64;
  int lin = blockIdx.y * gridDim.x + blockIdx.x;
  int xcd = lin & 7, idx = lin >> 3;
  int perx = gridDim.x, rows_per = gridDim.y >> 3;
  int by = xcd * rows_per + idx / perx;
  int bx = idx % perx;
  int bm = by * 128, bn = bx * 128;

  f32x4 acc[4][4];
  #pragma unroll
  for (int m = 0; m < 4; ++m)
    #pragma unroll
    for (int n = 0; n < 4; ++n)
      acc[m][n] = (f32x4){0.f, 0.f, 0.f, 0.f};

  for (int k0 = 0; k0 < K; k0 += 64) {
    #pragma unroll
    for (int i = 0; i < 4; ++i) {
      int c = i * 256 + w * 64 + ln;
      int r = c >> 3, cc = c & 7;
      gld16(&A[(size_t)(bm + r) * K + k0 + ((cc ^ (r & 7)) << 3)], &As[c << 3]);
    }
    #pragma unroll
    for (int i = 0; i < 4; ++i) {
      int c = i * 256 + w * 64 + ln;
      int r = c >> 3, cc = c & 7;
      gld16(&Bt[(size_t)(bn + r) * K + k0 + ((cc ^ (r & 7)) << 3)], &Bs[c << 3]);
    }
    __syncthreads();
    #pragma unroll
    for (int ks = 0; ks < 2; ++ks) {
      short8 a[4], b[4];
      #pragma unroll
      for (int m = 0; m < 4; ++m) {
        int row = wr + m * 16 + lo;
        a[m] = *(const short8*)&As[row * 64 + (((ks * 4 + hi) ^ (lo & 7)) << 3)];
      }
      #pragma unroll
      for (int n = 0; n < 4; ++n) {
        int row = wc + n * 16 + lo;
        b[n] = *(const short8*)&Bs[row * 64 + (((ks * 4 + hi) ^ (lo & 7)) << 3)];
      }
      #pragma unroll
      for (int m = 0; m < 4; ++m)
        #pragma unroll
        for (int n = 0; n < 4; ++n)
          acc[m][n] = MFMA16(a[m], b[n], acc[m][n]);
    }
    __syncthreads();
  }
  #pragma unroll
  for (int m = 0; m < 4; ++m)
    #pragma unroll
    for (int n = 0; n < 4; ++n) {
      int col = bn + wc + n * 16 + lo;
      int row0 = bm + wr + m * 16 + hi * 4;
      if (MODE == 0) {
        int type = col >> 9, hd = (col >> 6) & 7, e = col & 63;
        float bv = bias[col];
        if (type < 2) {
          u16* dst = (type == 0) ? oq : ok;
          #pragma unroll
          for (int r = 0; r < 4; ++r) {
            float v = acc[m][n][r] + bv;
            v = (v > 0.f) ? (v + 1.f) : __expf(v);
            if (type == 0) v *= 0.18033688f;   // 0.125 * log2(e)
            int row = row0 + r;
            dst[(size_t)(((row >> 10) << 3) + hd) * 65536 + (size_t)(row & 1023) * 64 + e] = f2bf(v);
          }
        } else {
          float v0 = acc[m][n][0] + bv, v1 = acc[m][n][1] + bv;
          float v2 = acc[m][n][2] + bv, v3 = acc[m][n][3] + bv;
          i32x2 d = {(int)cvtpk(v0, v1), (int)cvtpk(v2, v3)};
          int bidx = row0 >> 10;
          *(i32x2*)&ov[(size_t)((bidx << 3) + hd) * 65536 + (size_t)e * 1024 + (row0 & 1023)] = d;
        }
      } else {
        #pragma unroll
        for (int r = 0; r < 4; ++r)
          fo[(size_t)(row0 + r) * 512 + col] = acc[m][n][r] + bias[col];
      }
    }
}

// ---------------- flash attention: software-pipelined (QK(t+1) || SM(t)) -----
// 4-slot K/V LDS ring (stage distance 3); 4 waves x 64 q-cols; swapped 32x32.
// qh/kh [bh][1024][64] (q pre: (elu+1)/8*log2e); vt [bh][64][1024] (V^T)
// ub [1024][32] (u*log2e); vtb [1024][32] (v^T, direct global reads)
__global__ __launch_bounds__(256, 2) void attnpipe(
    const u16* __restrict__ qh, const u16* __restrict__ kh,
    const u16* __restrict__ vt, const u16* __restrict__ ub,
    const u16* __restrict__ vtb, u16* __restrict__ ob) {
  __shared__ __align__(16) u16 Ks[4][64 * 64];   // 32 KB, chunk-swizzled
  __shared__ __align__(16) u16 Vs[4][64 * 64];   // 32 KB, chunk-swizzled
  int tid = threadIdx.x;
  int w = tid >> 6, ln = tid & 63;
  int m32 = ln & 31, h = ln >> 5;
  int lin = blockIdx.y * gridDim.x + blockIdx.x;
  int xcd = lin & 7, idx = lin >> 3;           // idx in [0,64)
  int bh = xcd * 16 + (idx >> 2);
  int q0 = (idx & 3) * 256 + w * 64;
  size_t bhb = (size_t)bh << 16;

  short8 qf[2][4], uf[2][2];
  #pragma unroll
  for (int s = 0; s < 2; ++s) {
    int qc = q0 + s * 32 + m32;
    #pragma unroll
    for (int ks = 0; ks < 4; ++ks)
      qf[s][ks] = *(const short8*)&qh[bhb + (size_t)qc * 64 + ks * 16 + h * 8];
    #pragma unroll
    for (int k2 = 0; k2 < 2; ++k2)
      uf[s][k2] = *(const short8*)&ub[(size_t)qc * 32 + k2 * 16 + h * 8];
  }

  auto STAGE = [&](int slot, int kv) {
    #pragma unroll
    for (int i = 0; i < 2; ++i) {
      int c = i * 256 + w * 64 + ln;
      int r = c >> 3, cc = c & 7;
      gld16(&kh[bhb + (size_t)(kv + r) * 64 + ((cc ^ (r & 7)) << 3)], &Ks[slot][c << 3]);
      gld16(&vt[bhb + (size_t)r * 1024 + kv + ((cc ^ (r & 7)) << 3)], &Vs[slot][c << 3]);
    }
  };

  f32x16 zro;
  #pragma unroll
  for (int i = 0; i < 16; ++i) zro[i] = 0.f;
  f32x16 o[2][2];
  #pragma unroll
  for (int s = 0; s < 2; ++s) { o[s][0] = zro; o[s][1] = zro; }
  f32x16 sA[2][2], sB[2][2];
  float mrun[2] = {-3e38f, -3e38f}, lrun[2] = {0.f, 0.f};

// QK cluster for tile (TT)+1 into SN, reading Ks slot ((TT)+1)&3.
// First MFMA per accumulator seeds C with zro (no per-tile zero-init movs).
#define QK_CL(TT, SN)                                                          \
  {                                                                            \
    const int kvn_ = ((TT) + 1) * 64;                                          \
    const int kb_ = ((TT) + 1) & 3;                                            \
    short8 tfa_[2], tfb_[2];                                                   \
    _Pragma("unroll")                                                          \
    for (int k2 = 0; k2 < 2; ++k2) {                                           \
      tfa_[k2] = *(const short8*)&vtb[(size_t)(kvn_ + m32) * 32 + k2 * 16 + h * 8]; \
      tfb_[k2] = *(const short8*)&vtb[(size_t)(kvn_ + 32 + m32) * 32 + k2 * 16 + h * 8]; \
    }                                                                          \
    _Pragma("unroll")                                                          \
    for (int ks = 0; ks < 4; ++ks) {                                           \
      short8 k0f_ = *(const short8*)&Ks[kb_][m32 * 64 + (((ks * 2 + h) ^ (m32 & 7)) << 3)]; \
      short8 k1f_ = *(const short8*)&Ks[kb_][(32 + m32) * 64 + (((ks * 2 + h) ^ (m32 & 7)) << 3)]; \
      _Pragma("unroll")                                                        \
      for (int s = 0; s < 2; ++s) {                                            \
        SN[s][0] = MFMA32(k0f_, qf[s][ks], (ks == 0) ? zro : SN[s][0]);        \
        SN[s][1] = MFMA32(k1f_, qf[s][ks], (ks == 0) ? zro : SN[s][1]);        \
      }                                                                        \
    }                                                                          \
    _Pragma("unroll")                                                          \
    for (int k2 = 0; k2 < 2; ++k2)                                             \
      _Pragma("unroll")                                                        \
      for (int s = 0; s < 2; ++s) {                                            \
        SN[s][0] = MFMA32(tfa_[k2], uf[s][k2], SN[s][0]);                      \
        SN[s][1] = MFMA32(tfb_[k2], uf[s][k2], SN[s][1]);                      \
      }                                                                        \
  }

// softmax + PV for tile (T) from SC, V from Vs slot (P_)
#define SM_PV(PP, SC)                                                          \
  {                                                                            \
    _Pragma("unroll")                                                          \
    for (int s = 0; s < 2; ++s) {                                              \
      float pm = fmaxf(SC[s][0][0], SC[s][0][1]);                              \
      _Pragma("unroll")                                                        \
      for (int i = 2; i < 16; i += 2) pm = fmaxf(pm, fmaxf(SC[s][0][i], SC[s][0][i + 1])); \
      _Pragma("unroll")                                                        \
      for (int i = 0; i < 16; i += 2) pm = fmaxf(pm, fmaxf(SC[s][1][i], SC[s][1][i + 1])); \
      pm = fmaxf(pm, __shfl_xor(pm, 32));                                      \
      if (!__all(pm - mrun[s] <= 11.5f)) {                                     \
        float nm = fmaxf(mrun[s], pm);                                         \
        float al = exp2v(mrun[s] - nm);                                        \
        _Pragma("unroll")                                                      \
        for (int i = 0; i < 16; ++i) { o[s][0][i] *= al; o[s][1][i] *= al; }   \
        lrun[s] *= al; mrun[s] = nm;                                           \
      }                                                                        \
    }                                                                          \
    _Pragma("unroll")                                                          \
    for (int hf = 0; hf < 2; ++hf) {                                           \
      unsigned pk_[2][4][2];                                                   \
      _Pragma("unroll")                                                        \
      for (int s = 0; s < 2; ++s) {                                            \
        float ls = 0.f;                                                        \
        _Pragma("unroll")                                                      \
        for (int i = 0; i < 16; ++i) { float p = exp2v(SC[s][hf][i] - mrun[s]); SC[s][hf][i] = p; ls += p; } \
        lrun[s] += ls;                                                         \
        _Pragma("unroll")                                                      \
        for (int r8 = 0; r8 < 4; ++r8) {                                       \
          pk_[s][r8][0] = cvtpk(SC[s][hf][r8 * 4 + 0], SC[s][hf][r8 * 4 + 1]); \
          pk_[s][r8][1] = cvtpk(SC[s][hf][r8 * 4 + 2], SC[s][hf][r8 * 4 + 3]); \
        }                                                                      \
      }                                                                        \
      _Pragma("unroll")                                                        \
      for (int msl = 0; msl < 2; ++msl) {                                      \
        const int ms_ = hf * 2 + msl;                                          \
        short8 v0_ = *(const short8*)&Vs[PP][m32 * 64 + (((ms_ * 2 + h) ^ (m32 & 7)) << 3)]; \
        short8 v1_ = *(const short8*)&Vs[PP][(32 + m32) * 64 + (((ms_ * 2 + h) ^ (m32 & 7)) << 3)]; \
        _Pragma("unroll")                                                      \
        for (int s = 0; s < 2; ++s) {                                          \
          unsigned a0 = pk_[s][2 * msl][0], b0 = pk_[s][2 * msl + 1][0];       \
          unsigned a1 = pk_[s][2 * msl][1], b1 = pk_[s][2 * msl + 1][1];       \
          asm("v_permlane32_swap_b32 %0, %1" : "+v"(a0), "+v"(b0));            \
          asm("v_permlane32_swap_b32 %0, %1" : "+v"(a1), "+v"(b1));            \
          union { i32x4 i; short8 s8; } pu;                                    \
          pu.i = (i32x4){(int)a0, (int)a1, (int)b0, (int)b1};                  \
          o[s][0] = MFMA32(v0_, pu.s8, o[s][0]);                               \
          o[s][1] = MFMA32(v1_, pu.s8, o[s][1]);                               \
        }                                                                      \
      }                                                                        \
    }                                                                          \
  }

// one pipeline step: stage tile T+3, issue QK(T+1) MFMAs, then SM+PV(T) VALU
// overlaps the in-flight matrix work. Barrier drains stage issued at top.
#define ATTN_ITER(T, SC, SN, DOSTG, DOQK)                                      \
  {                                                                            \
    if (DOSTG) STAGE(((T) + 3) & 3, ((T) + 3) * 64);                           \
    if (DOQK) QK_CL((T), SN);                                                  \
    SM_PV(((T) & 3), SC);                                                      \
    __syncthreads();                                                           \
  }

  // prologue: tiles 0,1,2 staged into slots 0,1,2; scores(0) -> sA
  STAGE(0, 0); STAGE(1, 64); STAGE(2, 128);
  __syncthreads();
  QK_CL(-1, sA);

  int t = 0;
  #pragma unroll 1
  for (int t2 = 0; t2 < 6; ++t2) {
    ATTN_ITER(t, sA, sB, 1, 1); ++t;
    ATTN_ITER(t, sB, sA, 1, 1); ++t;
  }
  ATTN_ITER(12, sA, sB, 1, 1);   // stages tile 15
  ATTN_ITER(13, sB, sA, 0, 1);
  ATTN_ITER(14, sA, sB, 0, 1);
  ATTN_ITER(15, sB, sA, 0, 0);

#undef ATTN_ITER
#undef SM_PV
#undef QK_CL

  // ---- finalize: per set, lane col q = q0+s*32+m32; e rows in o regs
  int b = bh >> 3, hd = bh & 7;
  #pragma unroll
  for (int s = 0; s < 2; ++s) {
    float lt = lrun[s] + __shfl_xor(lrun[s], 32);
    float li = 1.f / lt;
    size_t orow = ((size_t)(b * 1024 + q0 + s * 32 + m32)) * 512 + hd * 64;
    #pragma unroll
    for (int et = 0; et < 2; ++et)
      #pragma unroll
      for (int r8 = 0; r8 < 4; ++r8) {
        float v0 = o[s][et][r8 * 4 + 0] * li;
        float v1 = o[s][et][r8 * 4 + 1] * li;
        float v2 = o[s][et][r8 * 4 + 2] * li;
        float v3 = o[s][et][r8 * 4 + 3] * li;
        i32x2 d = {(int)cvtpk(v0, v1), (int)cvtpk(v2, v3)};
        *(i32x2*)&ob[orow + et * 32 + 8 * r8 + 4 * h] = d;
      }
  }
}

extern "C" void kernel_launch(void* const* d_in, const int* in_sizes, int n_in,
                              void* d_out, int out_size, void* d_ws, size_t ws_size,
                              hipStream_t stream) {
  const float* x    = (const float*)d_in[0];   // [16384,512]
  const float* Wqkv = (const float*)d_in[1];   // [512,1536]
  const float* bqkv = (const float*)d_in[2];   // [1536]
  const float* Wout = (const float*)d_in[3];   // [512,512]
  const float* bout = (const float*)d_in[4];   // [512]
  const float* u    = (const float*)d_in[5];   // [1024,32]
  const float* vlr  = (const float*)d_in[6];   // [32,1024]
  float* out = (float*)d_out;

  char* ws = (char*)d_ws;
  u16* qh    = (u16*)(ws);                      // 16 MB  [bh][n][64]
  u16* kh    = (u16*)(ws + 16777216);           // 16 MB  [bh][n][64]
  u16* xb    = (u16*)(ws + 33554432);           // 16 MB  (gemm0 input)
  u16* ob    = (u16*)(ws + 33554432);           // 16 MB  (attn out, reuses xb)
  u16* vTg   = (u16*)(ws + 50331648);           // 16 MB  [bh][64][1024]
  u16* Wqkvt = (u16*)(ws + 67108864);           // 1.5 MB [1536][512]
  u16* Woutt = (u16*)(ws + 68681728);           // 0.5 MB [512][512]
  u16* ub    = (u16*)(ws + 69206016);           // 64 KB  [1024][32] (u*log2e)
  u16* vTb   = (u16*)(ws + 69271552);           // 64 KB  [1024][32]

  prep<<<5168, 256, 0, stream>>>(x, xb, u, ub, Wqkv, Wqkvt, Wout, Woutt, vlr, vTb);
  gemm128<0><<<dim3(12, 128), 256, 0, stream>>>(xb, Wqkvt, bqkv, qh, kh, vTg, nullptr);
  attnpipe<<<dim3(4, 128), 256, 0, stream>>>(qh, kh, vTg, ub, vTb, ob);
  gemm128<1><<<dim3(4, 128), 256, 0, stream>>>(ob, Woutt, bout, nullptr, nullptr, nullptr, out);
}

// Round 9
// 206.364 us; speedup vs baseline: 1.3339x; 1.3339x over previous
//
#include <hip/hip_runtime.h>
#include <hip/hip_bf16.h>

typedef unsigned short u16;
typedef __attribute__((ext_vector_type(8))) short short8;
typedef __attribute__((ext_vector_type(4))) float f32x4;
typedef __attribute__((ext_vector_type(16))) float f32x16;
typedef __attribute__((ext_vector_type(4))) int i32x4;
typedef __attribute__((ext_vector_type(2))) int i32x2;

#define MFMA16(a,b,c) __builtin_amdgcn_mfma_f32_16x16x32_bf16((a),(b),(c),0,0,0)
#define MFMA32(a,b,c) __builtin_amdgcn_mfma_f32_32x32x16_bf16((a),(b),(c),0,0,0)

__device__ __forceinline__ u16 f2bf(float f) {
  union { float f; unsigned int u; } x; x.f = f;
  unsigned int u = x.u;
  return (u16)((u + 0x7fffu + ((u >> 16) & 1u)) >> 16);  // RNE
}

// v_cvt_pk_bf16_f32: dst = {hi: bf16(b), lo: bf16(a)}
__device__ __forceinline__ unsigned cvtpk(float a, float b) {
  unsigned r;
  asm("v_cvt_pk_bf16_f32 %0, %1, %2" : "=v"(r) : "v"(a), "v"(b));
  return r;
}

// v_exp_f32: 2^x
__device__ __forceinline__ float exp2v(float x) {
  float r;
  asm("v_exp_f32 %0, %1" : "=v"(r) : "v"(x));
  return r;
}

// async global->LDS, 16B per lane (dst = wave-uniform base + lane*16)
__device__ __forceinline__ void gld16(const void* g, void* l) {
  __builtin_amdgcn_global_load_lds(
      (const __attribute__((address_space(1))) void*)g,
      (__attribute__((address_space(3))) void*)l, 16, 0, 0);
}

// ---------------- fused preprocessing ----------------------------------------
__global__ __launch_bounds__(256) void prep(
    const float* __restrict__ x, u16* __restrict__ xb,
    const float* __restrict__ u, u16* __restrict__ ub,
    const float* __restrict__ Wqkv, u16* __restrict__ Wqkvt,
    const float* __restrict__ Wout, u16* __restrict__ Woutt,
    const float* __restrict__ vlr, u16* __restrict__ vTb) {
  __shared__ float tile[32][33];
  int bid = blockIdx.x, tid = threadIdx.x;
  if (bid < 4112) {
    const float* in; u16* out; size_t i; float sc;
    if (bid < 4096) { in = x; out = xb; i = (size_t)bid * 256 + tid; sc = 1.f; }
    else { in = u; out = ub; i = (size_t)(bid - 4096) * 256 + tid; sc = 1.44269504f; }
    f32x4 a = *(const f32x4*)(in + i * 8);
    f32x4 b = *(const f32x4*)(in + i * 8 + 4);
    union { short8 s; u16 us[8]; } r;
    #pragma unroll
    for (int j = 0; j < 4; ++j) { r.us[j] = f2bf(a[j] * sc); r.us[4 + j] = f2bf(b[j] * sc); }
    *(short8*)&out[i * 8] = r.s;
    return;
  }
  int tb = bid - 4112;
  const float* in; u16* out; int rows, cols, bx, by;
  if (tb < 768)       { in = Wqkv; out = Wqkvt; rows = 512; cols = 1536; bx = tb % 48; by = tb / 48; }
  else if (tb < 1024) { int q = tb - 768; in = Wout; out = Woutt; rows = 512; cols = 512; bx = q % 16; by = q / 16; }
  else                { in = vlr; out = vTb; rows = 32; cols = 1024; bx = tb - 1024; by = 0; }
  int bc = bx * 32, br = by * 32;
  int tx = tid & 31, ty = tid >> 5;
  #pragma unroll
  for (int i = ty; i < 32; i += 8)
    tile[i][tx] = in[(size_t)(br + i) * cols + bc + tx];
  __syncthreads();
  #pragma unroll
  for (int i = ty; i < 32; i += 8)
    out[(size_t)(bc + i) * rows + br + tx] = f2bf(tile[tx][i]);
}

// ---------------- GEMM 128x128 tile, BK=64, 4 waves, global_load_lds ---------
// MODE 0: A=xb bf16 [16384,512], Bt=Wqkvt [1536,512]; epilogue: +bqkv,
//         q: (elu+1)*0.125*log2e -> qh[bh][n][64]; k: elu+1 -> kh;
//         v: written TRANSPOSED -> ov[bh][64 e][1024 n] (packed 8B stores)
// MODE 1: A=ob bf16 [16384,512], Bt=Woutt [512,512]; +bout -> fp32 out
template<int MODE>
__global__ __launch_bounds__(256) void gemm128(
    const u16* __restrict__ A, const u16* __restrict__ Bt,
    const float* __restrict__ bias,
    u16* __restrict__ oq, u16* __restrict__ ok, u16* __restrict__ ov,
    float* __restrict__ fo) {
  const int K = 512;
  __shared__ __align__(16) u16 As[128 * 64];
  __shared__ __align__(16) u16 Bs[128 * 64];
  int tid = threadIdx.x;
  int w = tid >> 6, ln = tid & 63, lo = ln & 15, hi = ln >> 4;
  int wr = (w >> 1) * 64, wc = (w & 1) * 64;
  int lin = blockIdx.y * gridDim.x + blockIdx.x;
  int xcd = lin & 7, idx = lin >> 3;
  int perx = gridDim.x, rows_per = gridDim.y >> 3;
  int by = xcd * rows_per + idx / perx;
  int bx = idx % perx;
  int bm = by * 128, bn = bx * 128;

  f32x4 acc[4][4];
  #pragma unroll
  for (int m = 0; m < 4; ++m)
    #pragma unroll
    for (int n = 0; n < 4; ++n)
      acc[m][n] = (f32x4){0.f, 0.f, 0.f, 0.f};

  for (int k0 = 0; k0 < K; k0 += 64) {
    #pragma unroll
    for (int i = 0; i < 4; ++i) {
      int c = i * 256 + w * 64 + ln;
      int r = c >> 3, cc = c & 7;
      gld16(&A[(size_t)(bm + r) * K + k0 + ((cc ^ (r & 7)) << 3)], &As[c << 3]);
    }
    #pragma unroll
    for (int i = 0; i < 4; ++i) {
      int c = i * 256 + w * 64 + ln;
      int r = c >> 3, cc = c & 7;
      gld16(&Bt[(size_t)(bn + r) * K + k0 + ((cc ^ (r & 7)) << 3)], &Bs[c << 3]);
    }
    __syncthreads();
    #pragma unroll
    for (int ks = 0; ks < 2; ++ks) {
      short8 a[4], b[4];
      #pragma unroll
      for (int m = 0; m < 4; ++m) {
        int row = wr + m * 16 + lo;
        a[m] = *(const short8*)&As[row * 64 + (((ks * 4 + hi) ^ (lo & 7)) << 3)];
      }
      #pragma unroll
      for (int n = 0; n < 4; ++n) {
        int row = wc + n * 16 + lo;
        b[n] = *(const short8*)&Bs[row * 64 + (((ks * 4 + hi) ^ (lo & 7)) << 3)];
      }
      #pragma unroll
      for (int m = 0; m < 4; ++m)
        #pragma unroll
        for (int n = 0; n < 4; ++n)
          acc[m][n] = MFMA16(a[m], b[n], acc[m][n]);
    }
    __syncthreads();
  }
  #pragma unroll
  for (int m = 0; m < 4; ++m)
    #pragma unroll
    for (int n = 0; n < 4; ++n) {
      int col = bn + wc + n * 16 + lo;
      int row0 = bm + wr + m * 16 + hi * 4;
      if (MODE == 0) {
        int type = col >> 9, hd = (col >> 6) & 7, e = col & 63;
        float bv = bias[col];
        if (type < 2) {
          u16* dst = (type == 0) ? oq : ok;
          #pragma unroll
          for (int r = 0; r < 4; ++r) {
            float v = acc[m][n][r] + bv;
            v = (v > 0.f) ? (v + 1.f) : __expf(v);
            if (type == 0) v *= 0.18033688f;   // 0.125 * log2(e)
            int row = row0 + r;
            dst[(size_t)(((row >> 10) << 3) + hd) * 65536 + (size_t)(row & 1023) * 64 + e] = f2bf(v);
          }
        } else {
          float v0 = acc[m][n][0] + bv, v1 = acc[m][n][1] + bv;
          float v2 = acc[m][n][2] + bv, v3 = acc[m][n][3] + bv;
          i32x2 d = {(int)cvtpk(v0, v1), (int)cvtpk(v2, v3)};
          int bidx = row0 >> 10;
          *(i32x2*)&ov[(size_t)((bidx << 3) + hd) * 65536 + (size_t)e * 1024 + (row0 & 1023)] = d;
        }
      } else {
        #pragma unroll
        for (int r = 0; r < 4; ++r)
          fo[(size_t)(row0 + r) * 512 + col] = acc[m][n][r] + bias[col];
      }
    }
}

// ---------------- flash attention: 2 waves x 64 q-cols, dbuf, grid 1024 ------
// Same per-wave structure as r6 attn64q (proven 64us, no spill), but 128-thread
// blocks and 4 blocks/CU so SIMD-coresident waves come from different blocks at
// decorrelated phases (one wave's MFMA overlaps the other's softmax VALU).
// qh/kh [bh][1024][64] bf16 (q pre: (elu+1)/8*log2e); vt [bh][64][1024] (V^T)
// ub [1024][32] bf16 (u*log2e); vtb [1024][32] bf16 (v^T, direct global reads)
__global__ __launch_bounds__(128, 2) void attn64q(
    const u16* __restrict__ qh, const u16* __restrict__ kh,
    const u16* __restrict__ vt, const u16* __restrict__ ub,
    const u16* __restrict__ vtb, u16* __restrict__ ob) {
  __shared__ __align__(16) u16 Ks[2][64 * 64];   // [m][d], chunk-swizzled
  __shared__ __align__(16) u16 Vs[2][64 * 64];   // [e][m], chunk-swizzled
  int tid = threadIdx.x;
  int w = tid >> 6, ln = tid & 63;
  int m32 = ln & 31, h = ln >> 5;
  // XCD swizzle: 16 contiguous bh per XCD (grid 1024 = 8 XCD x 128)
  int lin = blockIdx.y * gridDim.x + blockIdx.x;
  int xcd = lin & 7, idx = lin >> 3;           // idx in [0,128)
  int bh = xcd * 16 + (idx >> 3);
  int q0 = (idx & 7) * 128 + w * 64;
  size_t bhb = (size_t)bh << 16;

  short8 qf[2][4], uf[2][2];
  #pragma unroll
  for (int s = 0; s < 2; ++s) {
    int qc = q0 + s * 32 + m32;
    #pragma unroll
    for (int ks = 0; ks < 4; ++ks)
      qf[s][ks] = *(const short8*)&qh[bhb + (size_t)qc * 64 + ks * 16 + h * 8];
    #pragma unroll
    for (int k2 = 0; k2 < 2; ++k2)
      uf[s][k2] = *(const short8*)&ub[(size_t)qc * 32 + k2 * 16 + h * 8];
  }

  auto STAGE = [&](int buf, int kv) {
    #pragma unroll
    for (int i = 0; i < 4; ++i) {
      int c = i * 128 + w * 64 + ln;
      int r = c >> 3, cc = c & 7;
      gld16(&kh[bhb + (size_t)(kv + r) * 64 + ((cc ^ (r & 7)) << 3)], &Ks[buf][c << 3]);
      gld16(&vt[bhb + (size_t)r * 1024 + kv + ((cc ^ (r & 7)) << 3)], &Vs[buf][c << 3]);
    }
  };

  f32x16 zro;
  #pragma unroll
  for (int i = 0; i < 16; ++i) zro[i] = 0.f;
  f32x16 o[2][2];
  #pragma unroll
  for (int s = 0; s < 2; ++s) { o[s][0] = zro; o[s][1] = zro; }
  float mrun[2] = {-3e38f, -3e38f}, lrun[2] = {0.f, 0.f};

  int cur = 0;
  STAGE(0, 0);
  __syncthreads();

  for (int t = 0; t < 16; ++t) {
    int kv = t * 64;
    if (t < 15) STAGE(cur ^ 1, kv + 64);

    // low-rank bias A-frags: direct global (vtb is 64KB, L2-resident)
    short8 tf[2][2];
    #pragma unroll
    for (int k2 = 0; k2 < 2; ++k2) {
      tf[k2][0] = *(const short8*)&vtb[(size_t)(kv + m32) * 32 + k2 * 16 + h * 8];
      tf[k2][1] = *(const short8*)&vtb[(size_t)(kv + 32 + m32) * 32 + k2 * 16 + h * 8];
    }

    // ---- S'^T = K*Q + vtb*ub  (lane col = q; [set][kv-half]); ks==0 seeds zro
    f32x16 sA[2][2];
    __builtin_amdgcn_s_setprio(1);
    #pragma unroll
    for (int ks = 0; ks < 4; ++ks) {
      short8 k0f = *(const short8*)&Ks[cur][m32 * 64 + (((ks * 2 + h) ^ (m32 & 7)) << 3)];
      short8 k1f = *(const short8*)&Ks[cur][(32 + m32) * 64 + (((ks * 2 + h) ^ (m32 & 7)) << 3)];
      #pragma unroll
      for (int s = 0; s < 2; ++s) {
        sA[s][0] = MFMA32(k0f, qf[s][ks], (ks == 0) ? zro : sA[s][0]);
        sA[s][1] = MFMA32(k1f, qf[s][ks], (ks == 0) ? zro : sA[s][1]);
      }
    }
    #pragma unroll
    for (int k2 = 0; k2 < 2; ++k2)
      #pragma unroll
      for (int s = 0; s < 2; ++s) {
        sA[s][0] = MFMA32(tf[k2][0], uf[s][k2], sA[s][0]);
        sA[s][1] = MFMA32(tf[k2][1], uf[s][k2], sA[s][1]);
      }
    __builtin_amdgcn_s_setprio(0);

    // ---- online softmax per set (exp2 domain, defer-max THR=8*log2e)
    unsigned pk[2][2][4][2];
    #pragma unroll
    for (int s = 0; s < 2; ++s) {
      float pm = fmaxf(sA[s][0][0], sA[s][0][1]);
      #pragma unroll
      for (int i = 2; i < 16; i += 2) pm = fmaxf(fmaxf(pm, sA[s][0][i]), sA[s][0][i + 1]);
      #pragma unroll
      for (int i = 0; i < 16; i += 2) pm = fmaxf(fmaxf(pm, sA[s][1][i]), sA[s][1][i + 1]);
      pm = fmaxf(pm, __shfl_xor(pm, 32));
      if (!__all(pm - mrun[s] <= 11.5f)) {
        float nm = fmaxf(mrun[s], pm);
        float al = exp2v(mrun[s] - nm);
        #pragma unroll
        for (int i = 0; i < 16; ++i) { o[s][0][i] *= al; o[s][1][i] *= al; }
        lrun[s] *= al;
        mrun[s] = nm;
      }
      float ls = 0.f;
      #pragma unroll
      for (int i = 0; i < 16; ++i) { float p = exp2v(sA[s][0][i] - mrun[s]); sA[s][0][i] = p; ls += p; }
      #pragma unroll
      for (int i = 0; i < 16; ++i) { float p = exp2v(sA[s][1][i] - mrun[s]); sA[s][1][i] = p; ls += p; }
      lrun[s] += ls;
      #pragma unroll
      for (int hf = 0; hf < 2; ++hf)
        #pragma unroll
        for (int r8 = 0; r8 < 4; ++r8) {
          pk[s][hf][r8][0] = cvtpk(sA[s][hf][r8 * 4 + 0], sA[s][hf][r8 * 4 + 1]);
          pk[s][hf][r8][1] = cvtpk(sA[s][hf][r8 * 4 + 2], sA[s][hf][r8 * 4 + 3]);
        }
    }

    // ---- PV: each V A-frag pair feeds both q-sets
    #pragma unroll
    for (int ms = 0; ms < 4; ++ms) {
      int kvt = ms >> 1, msl = ms & 1;
      short8 v0 = *(const short8*)&Vs[cur][m32 * 64 + (((ms * 2 + h) ^ (m32 & 7)) << 3)];
      short8 v1 = *(const short8*)&Vs[cur][(32 + m32) * 64 + (((ms * 2 + h) ^ (m32 & 7)) << 3)];
      #pragma unroll
      for (int s = 0; s < 2; ++s) {
        unsigned a0 = pk[s][kvt][2 * msl][0], b0 = pk[s][kvt][2 * msl + 1][0];
        unsigned a1 = pk[s][kvt][2 * msl][1], b1 = pk[s][kvt][2 * msl + 1][1];
        asm("v_permlane32_swap_b32 %0, %1" : "+v"(a0), "+v"(b0));
        asm("v_permlane32_swap_b32 %0, %1" : "+v"(a1), "+v"(b1));
        union { i32x4 i; short8 s8; } pu;
        pu.i = (i32x4){(int)a0, (int)a1, (int)b0, (int)b1};
        __builtin_amdgcn_s_setprio(1);
        o[s][0] = MFMA32(v0, pu.s8, o[s][0]);
        o[s][1] = MFMA32(v1, pu.s8, o[s][1]);
        __builtin_amdgcn_s_setprio(0);
      }
    }
    __syncthreads();   // drains prefetch vmcnt + all ds reads of buf[cur]
    cur ^= 1;
  }

  // ---- finalize: per set, lane col q = q0+s*32+m32; e rows in o regs
  int b = bh >> 3, hd = bh & 7;
  #pragma unroll
  for (int s = 0; s < 2; ++s) {
    float lt = lrun[s] + __shfl_xor(lrun[s], 32);
    float li = 1.f / lt;
    size_t orow = ((size_t)(b * 1024 + q0 + s * 32 + m32)) * 512 + hd * 64;
    #pragma unroll
    for (int et = 0; et < 2; ++et)
      #pragma unroll
      for (int r8 = 0; r8 < 4; ++r8) {
        float v0 = o[s][et][r8 * 4 + 0] * li;
        float v1 = o[s][et][r8 * 4 + 1] * li;
        float v2 = o[s][et][r8 * 4 + 2] * li;
        float v3 = o[s][et][r8 * 4 + 3] * li;
        i32x2 d = {(int)cvtpk(v0, v1), (int)cvtpk(v2, v3)};
        *(i32x2*)&ob[orow + et * 32 + 8 * r8 + 4 * h] = d;
      }
  }
}

extern "C" void kernel_launch(void* const* d_in, const int* in_sizes, int n_in,
                              void* d_out, int out_size, void* d_ws, size_t ws_size,
                              hipStream_t stream) {
  const float* x    = (const float*)d_in[0];   // [16384,512]
  const float* Wqkv = (const float*)d_in[1];   // [512,1536]
  const float* bqkv = (const float*)d_in[2];   // [1536]
  const float* Wout = (const float*)d_in[3];   // [512,512]
  const float* bout = (const float*)d_in[4];   // [512]
  const float* u    = (const float*)d_in[5];   // [1024,32]
  const float* vlr  = (const float*)d_in[6];   // [32,1024]
  float* out = (float*)d_out;

  char* ws = (char*)d_ws;
  u16* qh    = (u16*)(ws);                      // 16 MB  [bh][n][64]
  u16* kh    = (u16*)(ws + 16777216);           // 16 MB  [bh][n][64]
  u16* xb    = (u16*)(ws + 33554432);           // 16 MB  (gemm0 input)
  u16* ob    = (u16*)(ws + 33554432);           // 16 MB  (attn out, reuses xb)
  u16* vTg   = (u16*)(ws + 50331648);           // 16 MB  [bh][64][1024]
  u16* Wqkvt = (u16*)(ws + 67108864);           // 1.5 MB [1536][512]
  u16* Woutt = (u16*)(ws + 68681728);           // 0.5 MB [512][512]
  u16* ub    = (u16*)(ws + 69206016);           // 64 KB  [1024][32] (u*log2e)
  u16* vTb   = (u16*)(ws + 69271552);           // 64 KB  [1024][32]

  prep<<<5168, 256, 0, stream>>>(x, xb, u, ub, Wqkv, Wqkvt, Wout, Woutt, vlr, vTb);
  gemm128<0><<<dim3(12, 128), 256, 0, stream>>>(xb, Wqkvt, bqkv, qh, kh, vTg, nullptr);
  attn64q<<<dim3(8, 128), 128, 0, stream>>>(qh, kh, vTg, ub, vTb, ob);
  gemm128<1><<<dim3(4, 128), 256, 0, stream>>>(ob, Woutt, bout, nullptr, nullptr, nullptr, out);
}